// Round 20
// baseline (263.236 us; speedup 1.0000x reference)
//
#include <hip/hip_runtime.h>
#include <hip/hip_bf16.h>

#define BB 8
#define NFQ 64
#define NUQ 1024
#define HH 8
#define SS 2176
#define QSC (0.08838834764831845f * 1.44269504088896340736f)

typedef __attribute__((ext_vector_type(8))) short short8;
typedef __attribute__((ext_vector_type(4))) float f32x4;
typedef __attribute__((ext_vector_type(2))) unsigned int uint2_t;
typedef unsigned short ubf;

__device__ __forceinline__ ubf f2bf(float x) {
    unsigned u = __float_as_uint(x);
    u = u + 0x7fffu + ((u >> 16) & 1u);
    return (ubf)(u >> 16);
}
__device__ __forceinline__ unsigned pkbf(float a, float b) {
    __hip_bfloat162 h = __float22bfloat162_rn(make_float2(a, b));
    union { __hip_bfloat162 hh; unsigned u; } c; c.hh = h;
    return c.u;
}
__device__ __forceinline__ float bf2f(short v) {
    return __uint_as_float(((unsigned)(ubf)v) << 16);
}

// ---------------- Kernel 0: weight transpose prep (verified; Q slices pre-scaled by QSC) ----------------
__global__ __launch_bounds__(256) void prep_kernel(
    const float* __restrict__ Wf, const float* __restrict__ Wu, const float* __restrict__ Wout,
    ubf* __restrict__ WfT, ubf* __restrict__ WuT, ubf* __restrict__ WoutT)
{
    __shared__ ubf tl[128 * 72];
    const int idx = blockIdx.x, tid = threadIdx.x;
    const float* src; ubf* dst; int F, dstride;
    bool scaleQ = false;
    if (idx < 48)       { F = 64; src = Wf + (size_t)idx * 64 * 128;        dst = WfT + (size_t)idx * 128 * 64;        dstride = 64; scaleQ = (idx % 3 == 0); }
    else if (idx < 96)  { F = 32; src = Wu + (size_t)(idx - 48) * 32 * 128; dst = WuT + (size_t)(idx - 48) * 128 * 32; dstride = 32; scaleQ = ((idx - 48) % 3 == 0); }
    else                { F = 64; int s = idx - 96; src = Wout + (size_t)s * 64 * 128; dst = WoutT + s * 64; dstride = 1024; }
    const float qs = scaleQ ? QSC : 1.0f;
    const int pitch = F + 8;
    for (int i = tid; i < F * 32; i += 256) {
        int f = i >> 5, d0 = (i & 31) * 4;
        f32x4 v = *(const f32x4*)&src[f * 128 + d0];
        tl[(d0 + 0) * pitch + f] = f2bf(v[0] * qs);
        tl[(d0 + 1) * pitch + f] = f2bf(v[1] * qs);
        tl[(d0 + 2) * pitch + f] = f2bf(v[2] * qs);
        tl[(d0 + 3) * pitch + f] = f2bf(v[3] * qs);
    }
    __syncthreads();
    if (F == 64) {
        int d = tid >> 1, half = tid & 1;
#pragma unroll
        for (int jj = 0; jj < 4; ++jj)
            *(short8*)&dst[(size_t)d * dstride + half * 32 + jj * 8] =
                *(const short8*)&tl[d * pitch + half * 32 + jj * 8];
    } else {
        int d = tid & 127, fh = tid >> 7;
#pragma unroll
        for (int jj = 0; jj < 2; ++jj)
            *(short8*)&dst[(size_t)d * dstride + fh * 16 + jj * 8] =
                *(const short8*)&tl[d * pitch + fh * 16 + jj * 8];
    }
}

// ---------------- Kernel 1: QKV projections via MFMA (verified r9; Q pre-scaled) ----------------
__global__ __launch_bounds__(256) void proj_kernel(
    const float* __restrict__ f0, const float* __restrict__ u0,
    const float* __restrict__ f1, const float* __restrict__ u1,
    const ubf* __restrict__ WfT, const ubf* __restrict__ WuT,
    const float* __restrict__ bfv, const float* __restrict__ buv,
    ubf* __restrict__ Qg, ubf* __restrict__ Kg, ubf* __restrict__ Vtg)
{
    __shared__ ubf xlds[32 * 64];
    __shared__ ubf outq[32 * 136];
    __shared__ ubf outk[32 * 136];
    __shared__ ubf outv[128 * 40];

    const int tid = threadIdx.x;
    const int bh = blockIdx.x / 17, j = blockIdx.x % 17;
    const int b = bh >> 3, h = bh & 7;
    const int w = tid >> 6, l = tid & 63, lg = l >> 4, dl = l & 15;
    const int dg0 = w * 2;

    const bool isF = (j == 0);
    const f32x4 zf = {0.f, 0.f, 0.f, 0.f};

    short8 af[3][2][2];
    f32x4 bv[3][2];

    const int up = isF ? 0 : ((j - 1) >> 3);
    const int ugrp = isF ? 0 : ((j - 1) & 7);
    const float* xpb = 0;
    if (!isF) xpb = (up ? u1 : u0) + (size_t)b * NUQ * 32;

    for (int c4 = 0; c4 < 4; ++c4) {
        int p, n0, s0;
        const float* xp;
        if (isF) {
            p = c4 >> 1; n0 = (c4 & 1) * 32;
            s0 = p ? 1088 + (c4 & 1) * 32 : (c4 & 1) * 32;
            xp = (p ? f1 : f0) + (size_t)b * NFQ * 64;
        } else {
            p = up; int c = ugrp * 4 + c4; n0 = 32 * c;
            s0 = (p ? 1152 : 64) + 32 * c;
            xp = xpb;
        }

        if (c4 == 0 || (isF && c4 == 2)) {
            if (isF) {
                const ubf* wt = WfT + (size_t)((h * 2 + p) * 3) * 8192;
#pragma unroll
                for (int k = 0; k < 3; ++k)
#pragma unroll
                    for (int g = 0; g < 2; ++g) {
                        af[k][g][0] = *(const short8*)&wt[(size_t)k * 8192 + ((dg0 + g) * 16 + dl) * 64 + lg * 8];
                        af[k][g][1] = *(const short8*)&wt[(size_t)k * 8192 + ((dg0 + g) * 16 + dl) * 64 + 32 + lg * 8];
                        bv[k][g] = *(const f32x4*)&bfv[((h * 2 + p) * 3 + k) * 128 + (dg0 + g) * 16 + 4 * lg];
                    }
            } else {
                const ubf* wt = WuT + (size_t)((h * 2 + p) * 3) * 4096;
#pragma unroll
                for (int k = 0; k < 3; ++k)
#pragma unroll
                    for (int g = 0; g < 2; ++g) {
                        af[k][g][0] = *(const short8*)&wt[(size_t)k * 4096 + ((dg0 + g) * 16 + dl) * 32 + lg * 8];
                        bv[k][g] = *(const f32x4*)&buv[((h * 2 + p) * 3 + k) * 128 + (dg0 + g) * 16 + 4 * lg];
                    }
            }
            bv[0][0] = bv[0][0] * QSC;
            bv[0][1] = bv[0][1] * QSC;
        }

        if (isF) {
            int row = tid >> 3, g = tid & 7;
            const float* s = &xp[(size_t)(n0 + row) * 64 + g * 8];
            f32x4 v0 = *(const f32x4*)&s[0];
            f32x4 v1 = *(const f32x4*)&s[4];
            union { unsigned u[4]; short8 s8; } pk;
            pk.u[0] = pkbf(v0[0], v0[1]); pk.u[1] = pkbf(v0[2], v0[3]);
            pk.u[2] = pkbf(v1[0], v1[1]); pk.u[3] = pkbf(v1[2], v1[3]);
            *(short8*)&xlds[row * 64 + ((g ^ (row & 7)) * 8)] = pk.s8;
        } else if (tid < 128) {
            int row = tid >> 2, g = tid & 3;
            const float* s = &xp[(size_t)(n0 + row) * 32 + g * 8];
            f32x4 v0 = *(const f32x4*)&s[0];
            f32x4 v1 = *(const f32x4*)&s[4];
            union { unsigned u[4]; short8 s8; } pk;
            pk.u[0] = pkbf(v0[0], v0[1]); pk.u[1] = pkbf(v0[2], v0[3]);
            pk.u[2] = pkbf(v1[0], v1[1]); pk.u[3] = pkbf(v1[2], v1[3]);
            *(short8*)&xlds[row * 64 + ((g ^ (row & 7)) * 8)] = pk.s8;
        }
        __syncthreads();

        short8 bx0[2], bx1[2];
#pragma unroll
        for (int tile = 0; tile < 2; ++tile) {
            const int row = tile * 16 + dl;
            bx0[tile] = *(const short8*)&xlds[row * 64 + ((lg ^ (row & 7)) * 8)];
            if (isF)
                bx1[tile] = *(const short8*)&xlds[row * 64 + (((4 + lg) ^ (row & 7)) * 8)];
        }

#pragma unroll
        for (int k = 0; k < 3; ++k)
#pragma unroll
            for (int g = 0; g < 2; ++g)
#pragma unroll
                for (int tile = 0; tile < 2; ++tile) {
                    f32x4 acc = __builtin_amdgcn_mfma_f32_16x16x32_bf16(af[k][g][0], bx0[tile], zf, 0, 0, 0);
                    if (isF)
                        acc = __builtin_amdgcn_mfma_f32_16x16x32_bf16(af[k][g][1], bx1[tile], acc, 0, 0, 0);
                    if (k < 2) {
                        ubf* o = k ? outk : outq;
                        uint2_t wv;
                        wv.x = pkbf(acc[0] + bv[k][g][0], acc[1] + bv[k][g][1]);
                        wv.y = pkbf(acc[2] + bv[k][g][2], acc[3] + bv[k][g][3]);
                        *(uint2_t*)&o[(tile * 16 + dl) * 136 + (dg0 + g) * 16 + 4 * lg] = wv;
                    } else {
                        int pos = (dl & 3) + 8 * ((dl >> 2) & 3) + 4 * tile;
#pragma unroll
                        for (int r = 0; r < 4; ++r)
                            outv[((dg0 + g) * 16 + 4 * lg + r) * 40 + pos] = f2bf(acc[r] + bv[2][g][r]);
                    }
                }
        __syncthreads();

        {
            int row = tid >> 3, c16 = (tid & 7) * 16;
            size_t qbase = ((size_t)bh * SS + s0 + row) * 128 + c16;
            *(short8*)&Qg[qbase]     = *(const short8*)&outq[row * 136 + c16];
            *(short8*)&Qg[qbase + 8] = *(const short8*)&outq[row * 136 + c16 + 8];
            *(short8*)&Kg[qbase]     = *(const short8*)&outk[row * 136 + c16];
            *(short8*)&Kg[qbase + 8] = *(const short8*)&outk[row * 136 + c16 + 8];
            int dd = tid >> 1, half = tid & 1;
            size_t vbase = ((size_t)bh * 128 + dd) * SS + s0 + half * 16;
            *(short8*)&Vtg[vbase]     = *(const short8*)&outv[dd * 40 + half * 16];
            *(short8*)&Vtg[vbase + 8] = *(const short8*)&outv[dd * 40 + half * 16 + 8];
        }
    }
}

// ---------------- Kernel 2: flash attention — split-K 2-way (verified r19); lsv layout [half][b][q][8] ----------------
__global__ __launch_bounds__(512) void attn_kernel(
    const ubf* __restrict__ Qg, const ubf* __restrict__ Kg, const ubf* __restrict__ Vtg,
    ubf* __restrict__ Op, float* __restrict__ lsv)
{
    __shared__ ubf Klds[2][32 * 128];
    __shared__ ubf Vlds[2][128 * 32];

    const int tid = threadIdx.x;
    const int swz = (blockIdx.x & 7) * 144 + (blockIdx.x >> 3);  // 1152 = 8 XCD x 144, bijective
    const int hh = swz / 9;
    const int qc = swz % 9;
    const int bh = hh >> 1;
    const int half = hh & 1;
    const int kv0 = half * 1088;
    const int b = bh >> 3, h = bh & 7;
    const int w = tid >> 6, l = tid & 63, lg = l >> 4, dl = l & 15;
    int qbase = qc * 256 + w * 32;
    const bool qvalid = qbase < SS;          // wave-uniform
    if (!qvalid) qbase = SS - 32;
    const int qr0 = qbase + dl;

    const ubf* Qbh = Qg + (size_t)bh * SS * 128;
    const ubf* Kbh = Kg + (size_t)bh * SS * 128;
    const ubf* Vbh = Vtg + (size_t)bh * 128 * SS;
    ubf* Oph = Op + (size_t)half * ((size_t)BB * HH * SS * 128);

    short8 qfa[4], qfb[4];
#pragma unroll
    for (int dc = 0; dc < 4; ++dc) {
        qfa[dc] = *(const short8*)&Qbh[(size_t)qr0 * 128 + dc * 32 + lg * 8];
        qfb[dc] = *(const short8*)&Qbh[(size_t)(qr0 + 16) * 128 + dc * 32 + lg * 8];
    }

    f32x4 otA[8], otB[8];
    const f32x4 zf = {0.f, 0.f, 0.f, 0.f};
#pragma unroll
    for (int i = 0; i < 8; ++i) { otA[i] = zf; otB[i] = zf; }
    float lsA = 0.f, lsB = 0.f;

    const int skrow = tid >> 4, skc = tid & 15;
    const int svrow = tid >> 2, svc = tid & 3;
    const int vg = svc ^ ((svrow >> 1) & 3);
    const int ko = skrow * 128 + ((skc * 8) ^ ((skrow & 7) << 3));
    const int vo = svrow * 32 + vg * 8;
    const ubf* kp = &Kbh[(size_t)(kv0 + skrow) * 128 + skc * 8];
    const ubf* vp = &Vbh[(size_t)svrow * SS + kv0 + svc * 8];
    const int vcol = (lg ^ ((dl >> 1) & 3)) * 8;

    short8 kst, vst;
    kst = *(const short8*)&kp[0];
    vst = *(const short8*)&vp[0];
    *(short8*)&Klds[0][ko] = kst;
    *(short8*)&Vlds[0][vo] = vst;
    __syncthreads();

    int cur = 0;
    for (int it = 0; it < 34; ++it) {
        if (it < 33) {
            kst = *(const short8*)&kp[(size_t)(it + 1) * 32 * 128];
            vst = *(const short8*)&vp[(it + 1) * 32];
        }
        const ubf* Kc = Klds[cur];
        const ubf* Vc = Vlds[cur];

        if (qvalid) {   // wave-uniform: tail block's waves skip compute, keep staging+barriers
            f32x4 s0a = zf, s1a = zf, s0b = zf, s1b = zf;
#pragma unroll
            for (int dc = 0; dc < 4; ++dc) {
                const int col = (dc * 32 + lg * 8) ^ ((dl & 7) << 3);
                short8 k0 = *(const short8*)&Kc[dl * 128 + col];
                short8 k1 = *(const short8*)&Kc[(16 + dl) * 128 + col];
                s0a = __builtin_amdgcn_mfma_f32_16x16x32_bf16(k0, qfa[dc], s0a, 0, 0, 0);
                s1a = __builtin_amdgcn_mfma_f32_16x16x32_bf16(k1, qfa[dc], s1a, 0, 0, 0);
                s0b = __builtin_amdgcn_mfma_f32_16x16x32_bf16(k0, qfb[dc], s0b, 0, 0, 0);
                s1b = __builtin_amdgcn_mfma_f32_16x16x32_bf16(k1, qfb[dc], s1b, 0, 0, 0);
            }

            union { unsigned u[4]; short8 s; } Pa, Pb;
#define EXPPACK(lo, hi, P, lsum) { \
            float e0 = __builtin_amdgcn_exp2f(lo[0]); \
            float e1 = __builtin_amdgcn_exp2f(lo[1]); \
            float e2 = __builtin_amdgcn_exp2f(lo[2]); \
            float e3 = __builtin_amdgcn_exp2f(lo[3]); \
            float e4 = __builtin_amdgcn_exp2f(hi[0]); \
            float e5 = __builtin_amdgcn_exp2f(hi[1]); \
            float e6 = __builtin_amdgcn_exp2f(hi[2]); \
            float e7 = __builtin_amdgcn_exp2f(hi[3]); \
            lsum += ((e0 + e1) + (e2 + e3)) + ((e4 + e5) + (e6 + e7)); \
            P.u[0] = pkbf(e0, e1); P.u[1] = pkbf(e2, e3); \
            P.u[2] = pkbf(e4, e5); P.u[3] = pkbf(e6, e7); }
            EXPPACK(s0a, s1a, Pa, lsA);
            EXPPACK(s0b, s1b, Pb, lsB);
#undef EXPPACK

#pragma unroll
            for (int dt = 0; dt < 8; ++dt) {
                short8 vf = *(const short8*)&Vc[(dt * 16 + dl) * 32 + vcol];
                otA[dt] = __builtin_amdgcn_mfma_f32_16x16x32_bf16(vf, Pa.s, otA[dt], 0, 0, 0);
                otB[dt] = __builtin_amdgcn_mfma_f32_16x16x32_bf16(vf, Pb.s, otB[dt], 0, 0, 0);
            }
        }

        if (it < 33) {
            *(short8*)&Klds[cur ^ 1][ko] = kst;
            *(short8*)&Vlds[cur ^ 1][vo] = vst;
            cur ^= 1;
            __syncthreads();
        }
    }

    if (qvalid) {
        lsA += __shfl_xor(lsA, 16); lsA += __shfl_xor(lsA, 32);
        lsB += __shfl_xor(lsB, 16); lsB += __shfl_xor(lsB, 32);
        ubf* dstA = Oph + ((size_t)b * SS + qr0) * 1024 + h * 128;
        ubf* dstB = Oph + ((size_t)b * SS + qr0 + 16) * 1024 + h * 128;
#pragma unroll
        for (int dt = 0; dt < 8; ++dt) {
            uint2_t wA, wB;
            wA.x = pkbf(otA[dt][0], otA[dt][1]); wA.y = pkbf(otA[dt][2], otA[dt][3]);
            wB.x = pkbf(otB[dt][0], otB[dt][1]); wB.y = pkbf(otB[dt][2], otB[dt][3]);
            *(uint2_t*)&dstA[dt * 16 + 4 * lg] = wA;
            *(uint2_t*)&dstB[dt * 16 + 4 * lg] = wB;
        }
        if (l < 16) {
            // lsv[half][b][q][h], h innermost (vectorizable in outproj)
            float* lp = &lsv[(((size_t)half * BB + b) * SS + qbase) * 8 + h];
            lp[(size_t)l * 8]        = lsA;   // q = qbase + l
            lp[(size_t)(16 + l) * 8] = lsB;   // q = qbase + 16 + l
        }
    }
}

// ---------------- Kernel 3: output projection via MFMA (verified r9) + vectorized split-K merge ----------------
__global__ __launch_bounds__(256) void outproj_kernel(
    const ubf* __restrict__ Op, const float* __restrict__ lsv,
    const ubf* __restrict__ WoutT, const float* __restrict__ bout, float* __restrict__ out)
{
    __shared__ ubf alds[32 * 1024];
    const int tid = threadIdx.x;
    const int row0 = blockIdx.x * 32;
    const int bq = row0 / SS;
    const int q0 = row0 - bq * SS;
    const int w = tid >> 6, l = tid & 63, lg = l >> 4, dl = l & 15;
    const int dg0 = w * 2;
    const f32x4 zf = {0.f, 0.f, 0.f, 0.f};
    const size_t qkvE = (size_t)BB * HH * SS * 128;

#pragma unroll
    for (int pz = 0; pz < 2; ++pz) {
        int row = pz * 16 + (tid >> 4);
        int cl = tid & 15;
        int q = q0 + row;
        const float* lp0 = &lsv[(((size_t)0 * BB + bq) * SS + q) * 8];
        const float* lp1 = &lsv[(((size_t)1 * BB + bq) * SS + q) * 8];
        f32x4 l0a = *(const f32x4*)&lp0[0], l0b = *(const f32x4*)&lp0[4];
        f32x4 l1a = *(const f32x4*)&lp1[0], l1b = *(const f32x4*)&lp1[4];
        float invl[8];
#pragma unroll
        for (int jj = 0; jj < 4; ++jj) {
            invl[jj]     = __builtin_amdgcn_rcpf(l0a[jj] + l1a[jj]);
            invl[4 + jj] = __builtin_amdgcn_rcpf(l0b[jj] + l1b[jj]);
        }
#pragma unroll
        for (int jj = 0; jj < 8; ++jj) {   // jj = head
            int g = cl + 16 * jj;
            size_t idx = (size_t)(row0 + row) * 1024 + g * 8;
            short8 v0 = *(const short8*)&Op[idx];
            short8 v1 = *(const short8*)&Op[qkvE + idx];
            float iv = invl[jj];
            union { unsigned u[4]; short8 s8; } pk;
            pk.u[0] = pkbf((bf2f(v0[0]) + bf2f(v1[0])) * iv, (bf2f(v0[1]) + bf2f(v1[1])) * iv);
            pk.u[1] = pkbf((bf2f(v0[2]) + bf2f(v1[2])) * iv, (bf2f(v0[3]) + bf2f(v1[3])) * iv);
            pk.u[2] = pkbf((bf2f(v0[4]) + bf2f(v1[4])) * iv, (bf2f(v0[5]) + bf2f(v1[5])) * iv);
            pk.u[3] = pkbf((bf2f(v0[6]) + bf2f(v1[6])) * iv, (bf2f(v0[7]) + bf2f(v1[7])) * iv);
            *(short8*)&alds[row * 1024 + ((g ^ (row & 7)) * 8)] = pk.s8;
        }
    }
    __syncthreads();

    f32x4 acc[2][2];
    acc[0][0] = zf; acc[0][1] = zf; acc[1][0] = zf; acc[1][1] = zf;

    for (int dc = 0; dc < 32; ++dc) {
        short8 a0 = *(const short8*)&WoutT[(size_t)((dg0 + 0) * 16 + dl) * 1024 + dc * 32 + lg * 8];
        short8 a1 = *(const short8*)&WoutT[(size_t)((dg0 + 1) * 16 + dl) * 1024 + dc * 32 + lg * 8];
        short8 b0 = *(const short8*)&alds[dl * 1024 + (((dc * 4 + lg) ^ (dl & 7)) * 8)];
        short8 b1 = *(const short8*)&alds[(16 + dl) * 1024 + (((dc * 4 + lg) ^ (dl & 7)) * 8)];
        acc[0][0] = __builtin_amdgcn_mfma_f32_16x16x32_bf16(a0, b0, acc[0][0], 0, 0, 0);
        acc[0][1] = __builtin_amdgcn_mfma_f32_16x16x32_bf16(a0, b1, acc[0][1], 0, 0, 0);
        acc[1][0] = __builtin_amdgcn_mfma_f32_16x16x32_bf16(a1, b0, acc[1][0], 0, 0, 0);
        acc[1][1] = __builtin_amdgcn_mfma_f32_16x16x32_bf16(a1, b1, acc[1][1], 0, 0, 0);
    }

#pragma unroll
    for (int g = 0; g < 2; ++g) {
        f32x4 bb = *(const f32x4*)&bout[(dg0 + g) * 16 + 4 * lg];
#pragma unroll
        for (int tile = 0; tile < 2; ++tile) {
            f32x4 o = acc[g][tile] + bb;
            *(f32x4*)&out[((size_t)row0 + tile * 16 + dl) * 128 + (dg0 + g) * 16 + 4 * lg] = o;
        }
    }
}

extern "C" void kernel_launch(void* const* d_in, const int* in_sizes, int n_in,
                              void* d_out, int out_size, void* d_ws, size_t ws_size,
                              hipStream_t stream) {
    const float* f0  = (const float*)d_in[0];
    const float* u0  = (const float*)d_in[1];
    const float* f1  = (const float*)d_in[2];
    const float* u1  = (const float*)d_in[3];
    const float* Wf  = (const float*)d_in[4];
    const float* bfv = (const float*)d_in[5];
    const float* Wu  = (const float*)d_in[6];
    const float* buv = (const float*)d_in[7];
    const float* Wout = (const float*)d_in[8];
    const float* bout = (const float*)d_in[9];
    float* out = (float*)d_out;

    char* ws = (char*)d_ws;
    const size_t qkv = (size_t)BB * HH * SS * 128 * sizeof(ubf); // 35,651,584
    ubf* Qg  = (ubf*)ws;
    ubf* Kg  = (ubf*)(ws + qkv);
    ubf* Vtg = (ubf*)(ws + 2 * qkv);
    ubf* Op  = (ubf*)(ws + 3 * qkv);
    float* lsv = (float*)(ws + 5 * qkv);             // [2][8][2176][8] f32 = 1,114,112 B
    ubf* WfT   = (ubf*)(ws + 3 * qkv);
    ubf* WuT   = (ubf*)(ws + 3 * qkv + 786432);
    ubf* WoutT = (ubf*)(ws + 5 * qkv + 1114112);

    prep_kernel<<<dim3(112), dim3(256), 0, stream>>>(Wf, Wu, Wout, WfT, WuT, WoutT);
    proj_kernel<<<dim3(64 * 17), dim3(256), 0, stream>>>(f0, u0, f1, u1, WfT, WuT, bfv, buv, Qg, Kg, Vtg);
    attn_kernel<<<dim3(1152), dim3(512), 0, stream>>>(Qg, Kg, Vtg, Op, lsv);
    outproj_kernel<<<dim3(544), dim3(256), 0, stream>>>(Op, lsv, WoutT, bout, out);
}